// Round 3
// baseline (1371.838 us; speedup 1.0000x reference)
//
#include <hip/hip_runtime.h>

#define NN 300000
#define NE 600000
#define NG 12000
#define HH 128
#define FA 9
#define VA 119
#define DA 9

// canonical f32 weight scratch offsets
#define OEMB 0
#define OW1  (FA*VA*DA)            // 9639
#define OB1  (OW1 + DA*HH)         // 10791
#define OW2  (OB1 + HH)            // 10919
#define OB2  (OW2 + HH*HH)         // 27303
#define OWFC (OB2 + HH)            // 27431
#define OBFC (OWFC + HH*HH)        // 43815
#define NWC  (OBFC + HH)           // 43943

typedef unsigned short u16;
typedef unsigned int u32;

__device__ __forceinline__ float bf2f(u16 u){
  union { u32 i; float f; } v; v.i = ((u32)u) << 16; return v.f;
}
__device__ __forceinline__ u16 f2bf(float f){
  union { float f; u32 i; } v; v.f = f;
  u32 x = v.i;
  return (u16)((x + 0x7FFFu + ((x >> 16) & 1u)) >> 16);
}
__device__ __forceinline__ float ldf(const void* p, int i, int isf32){
  return isf32 ? ((const float*)p)[i] : bf2f(((const u16*)p)[i]);
}

// ---- dtype detector: examine first 256 u16 words of atom_emb ----
// bf16 buffer: values ~N(0,0.02) -> every u16 decodes to |v| in [2^-31, 2^-2].
// f32 buffer read as u16: half the words are random mantissa bits -> ~12% pass.
__global__ void k_detect(const u16* __restrict__ emb, int* __restrict__ flag){
  __shared__ int cnt;
  int t = threadIdx.x;
  if (t == 0) cnt = 0;
  __syncthreads();
  u16 u = emb[t];
  int e = (u >> 7) & 0xFF;
  if (e >= 96 && e < 126) atomicAdd(&cnt, 1);
  __syncthreads();
  if (t == 0) flag[0] = (cnt >= 200) ? 0 : 1;   // 0 = bf16, 1 = f32
}

// ---- canonicalize all float params to f32 scratch ----
__global__ void k_cvtw(const void* emb, const void* W1, const void* b1,
                       const void* W2, const void* b2, const void* Wfc,
                       const void* bfc, const int* __restrict__ flag,
                       float* __restrict__ wc){
  int i = blockIdx.x * 256 + threadIdx.x;
  if (i >= NWC) return;
  int f = flag[0];
  float v;
  if      (i < OW1)  v = ldf(emb, i - OEMB, f);
  else if (i < OB1)  v = ldf(W1,  i - OW1,  f);
  else if (i < OW2)  v = ldf(b1,  i - OB1,  f);
  else if (i < OB2)  v = ldf(W2,  i - OW2,  f);
  else if (i < OWFC) v = ldf(b2,  i - OB2,  f);
  else if (i < OBFC) v = ldf(Wfc, i - OWFC, f);
  else               v = ldf(bfc, i - OBFC, f);
  wc[i] = v;
}

// ---- zero init: degf (aliased in dinv), agg1, pooled ----
__global__ void k_zero(float* __restrict__ degf, float* __restrict__ agg1,
                       float* __restrict__ pooled){
  int i = blockIdx.x * 256 + threadIdx.x;
  if (i < NN) degf[i] = 0.f;
  if (i < NG * HH) pooled[i] = 0.f;
  if (i < NN * DA) agg1[i] = 0.f;
}

// ---- in-degree histogram (float, into dinv buffer) ----
__global__ void k_deg(const int* __restrict__ dst, float* __restrict__ degf){
  int e = blockIdx.x * 256 + threadIdx.x;
  if (e < NE) atomicAdd(&degf[dst[e]], 1.0f);
}

// ---- dinv = rsqrt(deg + 1), in place ----
__global__ void k_dinv(float* __restrict__ dinv){
  int i = blockIdx.x * 256 + threadIdx.x;
  if (i < NN) dinv[i] = rsqrtf(dinv[i] + 1.0f);
}

// ---- multi_embed: h0[n,d] = sum_f emb[f, x[n,f], d]  (NN x 9, f32) ----
__global__ void k_embed0(const int* __restrict__ x, const float* __restrict__ wc,
                         float* __restrict__ h0){
  __shared__ float embS[FA * VA * DA];   // 38.6 KB
  int t = threadIdx.x;
  for (int i = t; i < FA * VA * DA; i += 256) embS[i] = wc[OEMB + i];
  __syncthreads();
  int n = blockIdx.x * 256 + t;
  if (n >= NN) return;
  int idx[FA];
  #pragma unroll
  for (int f = 0; f < FA; ++f) idx[f] = x[n * FA + f];
  #pragma unroll
  for (int d = 0; d < DA; ++d){
    float a = 0.f;
    #pragma unroll
    for (int f = 0; f < FA; ++f) a += embS[(f * VA + idx[f]) * DA + d];
    h0[n * DA + d] = a;
  }
}

// ---- layer-1 aggregation in 9-dim space, edge-wise atomics ----
__global__ void k_agg1(const int* __restrict__ src, const int* __restrict__ dst,
                       const float* __restrict__ dinv, const float* __restrict__ h0,
                       float* __restrict__ agg1){
  int e = blockIdx.x * 256 + threadIdx.x;
  if (e >= NE) return;
  int s = src[e], d = dst[e];
  float c = dinv[s] * dinv[d];
  #pragma unroll
  for (int j = 0; j < DA; ++j) atomicAdd(&agg1[d * DA + j], c * h0[s * DA + j]);
}

// ---- layer-1 self term (non-atomic: exclusive per (n,j), stream-ordered) ----
__global__ void k_self(const float* __restrict__ dinv, const float* __restrict__ h0,
                       float* __restrict__ agg1){
  int n = blockIdx.x * 256 + threadIdx.x;
  if (n >= NN) return;
  float c = dinv[n] * dinv[n];
  #pragma unroll
  for (int j = 0; j < DA; ++j) agg1[n * DA + j] += c * h0[n * DA + j];
}

// ---- fused layer2 + pooling. wave per item; item<NN: self, else edge. ----
// h1[s] = relu(agg1[s] @ W1 + b1) recomputed in-registers; scatter coef*h1
// into pooled[g] with f32 atomics. W2 is deferred past pooling (linearity).
__global__ void k_l2m(const float* __restrict__ agg1, const float* __restrict__ dinv,
                      const int* __restrict__ src, const int* __restrict__ dst,
                      const int* __restrict__ batch, const float* __restrict__ wc,
                      float* __restrict__ pooled){
  __shared__ float w1S[DA * HH];
  __shared__ float b1S[HH];
  int t = threadIdx.x;
  for (int i = t; i < DA * HH; i += 256) w1S[i] = wc[OW1 + i];
  if (t < HH) b1S[t] = wc[OB1 + t];
  __syncthreads();
  int item = blockIdx.x * 4 + (t >> 6);
  int lane = t & 63;
  if (item >= NN + NE) return;
  int s, g; float coef;
  if (item < NN){
    s = item; g = batch[item];
    float di = dinv[item]; coef = di * di;
  } else {
    int e = item - NN;
    s = src[e]; int dn = dst[e];
    g = batch[dn]; coef = dinv[s] * dinv[dn];
  }
  float a[DA];
  #pragma unroll
  for (int d = 0; d < DA; ++d) a[d] = agg1[s * DA + d];
  int k = lane * 2;
  float v0 = b1S[k], v1 = b1S[k + 1];
  #pragma unroll
  for (int d = 0; d < DA; ++d){
    v0 += a[d] * w1S[d * HH + k];
    v1 += a[d] * w1S[d * HH + k + 1];
  }
  v0 = fmaxf(v0, 0.f) * coef;
  v1 = fmaxf(v1, 0.f) * coef;
  atomicAdd(&pooled[(size_t)g * HH + k],     v0);
  atomicAdd(&pooled[(size_t)g * HH + k + 1], v1);
}

// ---- graph segment bounds via binary search on sorted batch ----
__global__ void k_gstart(const int* __restrict__ batch, int* __restrict__ gstart){
  int g = blockIdx.x * 256 + threadIdx.x;
  if (g > NG) return;
  if (g == NG){ gstart[NG] = NN; return; }
  int lo = 0, hi = NN;
  while (lo < hi){
    int mid = (lo + hi) >> 1;
    if (batch[mid] < g) lo = mid + 1; else hi = mid;
  }
  gstart[g] = lo;
}

// ---- gemb = (pooled/cnt) @ W2 + (cnt>0 ? b2 : 0) ----
__global__ void k_gemm1(const float* __restrict__ pooled, const float* __restrict__ wc,
                        const int* __restrict__ gstart, float* __restrict__ gemb){
  __shared__ float pl[2][HH];
  int t = threadIdx.x;
  int gg = t >> 7, k = t & 127;
  for (int p = blockIdx.x; p < NG / 2; p += gridDim.x){
    int g = p * 2 + gg;
    int cnt = gstart[g + 1] - gstart[g];
    float inv = 1.0f / (float)(cnt > 1 ? cnt : 1);
    pl[gg][k] = pooled[(size_t)g * HH + k] * inv;
    __syncthreads();
    float acc = (cnt > 0) ? wc[OB2 + k] : 0.f;
    #pragma unroll 8
    for (int d = 0; d < HH; ++d) acc += pl[gg][d] * wc[OW2 + d * HH + k];
    gemb[(size_t)g * HH + k] = acc;
    __syncthreads();
  }
}

// ---- out = gemb @ Wfc + bfc, store dtype per flag ----
__global__ void k_gemm2(const float* __restrict__ gemb, const float* __restrict__ wc,
                        const int* __restrict__ flag, void* __restrict__ out){
  __shared__ float pl[2][HH];
  int t = threadIdx.x;
  int isf32 = flag[0];
  int gg = t >> 7, k = t & 127;
  for (int p = blockIdx.x; p < NG / 2; p += gridDim.x){
    int g = p * 2 + gg;
    pl[gg][k] = gemb[(size_t)g * HH + k];
    __syncthreads();
    float acc = wc[OBFC + k];
    #pragma unroll 8
    for (int d = 0; d < HH; ++d) acc += pl[gg][d] * wc[OWFC + d * HH + k];
    if (isf32) ((float*)out)[(size_t)g * HH + k] = acc;
    else       ((u16*)out)[(size_t)g * HH + k] = f2bf(acc);
    __syncthreads();
  }
}

extern "C" void kernel_launch(void* const* d_in, const int* in_sizes, int n_in,
                              void* d_out, int out_size, void* d_ws, size_t ws_size,
                              hipStream_t stream){
  const int* x     = (const int*)d_in[0];
  const int* ei    = (const int*)d_in[1];
  const int* batch = (const int*)d_in[3];
  const void* aemb = d_in[4];
  const void* W1   = d_in[6];
  const void* b1   = d_in[7];
  const void* W2   = d_in[8];
  const void* b2   = d_in[9];
  const void* Wfc  = d_in[10];
  const void* bfc  = d_in[11];
  const int* srcp = ei;
  const int* dstp = ei + NE;

  // workspace layout — ~29.3 MB total
  char* p = (char*)d_ws;
  int*   flag   = (int*)p;                 p += 64;
  float* wc     = (float*)p;               p += sizeof(float) * ((NWC + 15) & ~15);
  float* dinv   = (float*)p;               p += sizeof(float) * NN;          // also degf
  int*   gstart = (int*)p;                 p += sizeof(int) * (NG + 4);
  float* pooled = (float*)p;               p += sizeof(float) * (size_t)NG * HH;
  float* h0     = (float*)p;               // NN*DA floats; gemb aliases (h0 dead by gemm1)
  float* gemb   = h0;
  float* agg1   = h0 + (size_t)NN * DA;    p += sizeof(float) * (size_t)NN * DA * 2;
  (void)p; (void)ws_size; (void)n_in; (void)in_sizes; (void)out_size;

  k_detect<<<1, 256, 0, stream>>>((const u16*)aemb, flag);
  k_cvtw  <<<(NWC + 255) / 256, 256, 0, stream>>>(aemb, W1, b1, W2, b2, Wfc, bfc, flag, wc);
  k_zero  <<<(NN * DA + 255) / 256, 256, 0, stream>>>(dinv, agg1, pooled);
  k_deg   <<<(NE + 255) / 256, 256, 0, stream>>>(dstp, dinv);
  k_dinv  <<<(NN + 255) / 256, 256, 0, stream>>>(dinv);
  k_embed0<<<(NN + 255) / 256, 256, 0, stream>>>(x, wc, h0);
  k_agg1  <<<(NE + 255) / 256, 256, 0, stream>>>(srcp, dstp, dinv, h0, agg1);
  k_self  <<<(NN + 255) / 256, 256, 0, stream>>>(dinv, h0, agg1);
  k_l2m   <<<(NN + NE) / 4, 256, 0, stream>>>(agg1, dinv, srcp, dstp, batch, wc, pooled);
  k_gstart<<<(NG + 256) / 256, 256, 0, stream>>>(batch, gstart);
  k_gemm1 <<<600, 256, 0, stream>>>(pooled, wc, gstart, gemb);
  k_gemm2 <<<600, 256, 0, stream>>>(gemb, wc, flag, d_out);
}

// Round 4
// 402.223 us; speedup vs baseline: 3.4106x; 3.4106x over previous
//
#include <hip/hip_runtime.h>

#define NN 300000
#define NE 600000
#define NG 12000
#define HH 128
#define FA 9
#define VA 119
#define DA 9
#define NCHUNK ((NN + 1023) / 1024)   // 293

// canonical f32 weight scratch offsets
#define OEMB 0
#define OW1  (FA*VA*DA)            // 9639
#define OB1  (OW1 + DA*HH)         // 10791
#define OW2  (OB1 + HH)            // 10919
#define OB2  (OW2 + HH*HH)         // 27303
#define OWFC (OB2 + HH)            // 27431
#define OBFC (OWFC + HH*HH)        // 43815
#define NWC  (OBFC + HH)           // 43943

typedef unsigned short u16;
typedef unsigned int u32;

__device__ __forceinline__ float bf2f(u16 u){
  union { u32 i; float f; } v; v.i = ((u32)u) << 16; return v.f;
}
__device__ __forceinline__ u16 f2bf(float f){
  union { float f; u32 i; } v; v.f = f;
  u32 x = v.i;
  return (u16)((x + 0x7FFFu + ((x >> 16) & 1u)) >> 16);
}
__device__ __forceinline__ float ldf(const void* p, int i, int isf32){
  return isf32 ? ((const float*)p)[i] : bf2f(((const u16*)p)[i]);
}

// ---- dtype detector (validated round 3: bf16 correctly identified) ----
__global__ void k_detect(const u16* __restrict__ emb, int* __restrict__ flag){
  __shared__ int cnt;
  int t = threadIdx.x;
  if (t == 0) cnt = 0;
  __syncthreads();
  u16 u = emb[t];
  int e = (u >> 7) & 0xFF;
  if (e >= 96 && e < 126) atomicAdd(&cnt, 1);
  __syncthreads();
  if (t == 0) flag[0] = (cnt >= 200) ? 0 : 1;   // 0 = bf16, 1 = f32
}

// ---- canonicalize all float params to f32 scratch ----
__global__ void k_cvtw(const void* emb, const void* W1, const void* b1,
                       const void* W2, const void* b2, const void* Wfc,
                       const void* bfc, const int* __restrict__ flag,
                       float* __restrict__ wc){
  int i = blockIdx.x * 256 + threadIdx.x;
  if (i >= NWC) return;
  int f = flag[0];
  float v;
  if      (i < OW1)  v = ldf(emb, i - OEMB, f);
  else if (i < OB1)  v = ldf(W1,  i - OW1,  f);
  else if (i < OW2)  v = ldf(b1,  i - OB1,  f);
  else if (i < OB2)  v = ldf(W2,  i - OW2,  f);
  else if (i < OWFC) v = ldf(b2,  i - OB2,  f);
  else if (i < OBFC) v = ldf(Wfc, i - OWFC, f);
  else               v = ldf(bfc, i - OBFC, f);
  wc[i] = v;
}

// ---- zero deg ----
__global__ void k_zero(int* __restrict__ deg){
  int i = blockIdx.x * 256 + threadIdx.x;
  if (i < NN) deg[i] = 0;
}

// ---- in-degree histogram (int atomics, low contention) ----
__global__ void k_deg(const int* __restrict__ dst, int* __restrict__ deg){
  int e = blockIdx.x * 256 + threadIdx.x;
  if (e < NE) atomicAdd(&deg[dst[e]], 1);
}

// ---- exclusive scan of deg -> rowoff (3-kernel) ----
__global__ void k_scan1(const int* __restrict__ deg, int* __restrict__ rowoff,
                        int* __restrict__ part){
  __shared__ int sh[256];
  int base = blockIdx.x * 1024;
  int t = threadIdx.x;
  int i0 = base + t * 4;
  int v0=0, v1=0, v2=0, v3=0;
  if (i0 + 0 < NN) v0 = deg[i0 + 0];
  if (i0 + 1 < NN) v1 = deg[i0 + 1];
  if (i0 + 2 < NN) v2 = deg[i0 + 2];
  if (i0 + 3 < NN) v3 = deg[i0 + 3];
  int tsum = v0 + v1 + v2 + v3;
  sh[t] = tsum;
  __syncthreads();
  for (int off = 1; off < 256; off <<= 1){
    int add = (t >= off) ? sh[t - off] : 0;
    __syncthreads();
    sh[t] += add;
    __syncthreads();
  }
  int run = sh[t] - tsum;
  if (t == 255) part[blockIdx.x] = sh[255];
  if (i0 + 0 < NN){ rowoff[i0 + 0] = run; run += v0; }
  if (i0 + 1 < NN){ rowoff[i0 + 1] = run; run += v1; }
  if (i0 + 2 < NN){ rowoff[i0 + 2] = run; run += v2; }
  if (i0 + 3 < NN){ rowoff[i0 + 3] = run; run += v3; }
}

__global__ void k_scan2(int* __restrict__ part){
  __shared__ int sh[512];
  int t = threadIdx.x;
  int v = (t < NCHUNK) ? part[t] : 0;
  sh[t] = v;
  __syncthreads();
  for (int off = 1; off < 512; off <<= 1){
    int add = (t >= off) ? sh[t - off] : 0;
    __syncthreads();
    sh[t] += add;
    __syncthreads();
  }
  if (t < NCHUNK) part[t] = sh[t] - v;
}

// degcur: deg on input, cursor on output (aliased buffer; per-element read-then-write)
__global__ void k_scan3(int* degcur, int* __restrict__ rowoff,
                        float* __restrict__ dinv, const int* __restrict__ part){
  int i = blockIdx.x * 256 + threadIdx.x;
  if (i < NN){
    float dv = (float)degcur[i];        // read deg BEFORE overwrite
    int r = rowoff[i] + part[i >> 10];
    rowoff[i] = r;
    degcur[i] = r;                      // cursor
    dinv[i] = rsqrtf(dv + 1.0f);
  }
  if (i == 0) rowoff[NN] = NE;
}

// ---- CSR fill ----
__global__ void k_fill(const int* __restrict__ src, const int* __restrict__ dst,
                       int* __restrict__ cursor, int* __restrict__ csrsrc){
  int e = blockIdx.x * 256 + threadIdx.x;
  if (e < NE){
    int pos = atomicAdd(&cursor[dst[e]], 1);
    csrsrc[pos] = src[e];
  }
}

// ---- multi_embed: h0[n,d] = sum_f emb[f, x[n,f], d] ----
__global__ void k_embed0(const int* __restrict__ x, const float* __restrict__ wc,
                         float* __restrict__ h0){
  __shared__ float embS[FA * VA * DA];   // 38.6 KB
  int t = threadIdx.x;
  for (int i = t; i < FA * VA * DA; i += 256) embS[i] = wc[OEMB + i];
  __syncthreads();
  int n = blockIdx.x * 256 + t;
  if (n >= NN) return;
  int idx[FA];
  #pragma unroll
  for (int f = 0; f < FA; ++f) idx[f] = x[n * FA + f];
  #pragma unroll
  for (int d = 0; d < DA; ++d){
    float a = 0.f;
    #pragma unroll
    for (int f = 0; f < FA; ++f) a += embS[(f * VA + idx[f]) * DA + d];
    h0[n * DA + d] = a;
  }
}

// ---- layer-1 aggregation via CSR gather (no atomics): agg1 = A' h0 ----
__global__ void k_l1csr(const float* __restrict__ h0, float* __restrict__ agg1,
                        const int* __restrict__ rowoff, const int* __restrict__ csrsrc,
                        const float* __restrict__ dinv){
  int n = blockIdx.x * 256 + threadIdx.x;
  if (n >= NN) return;
  float di = dinv[n];
  float c0 = di * di;
  float acc[DA];
  #pragma unroll
  for (int d = 0; d < DA; ++d) acc[d] = c0 * h0[n * DA + d];
  int s0 = rowoff[n], s1 = rowoff[n + 1];
  for (int j = s0; j < s1; ++j){
    int s = csrsrc[j];
    float c = dinv[s] * di;
    #pragma unroll
    for (int d = 0; d < DA; ++d) acc[d] += c * h0[s * DA + d];
  }
  #pragma unroll
  for (int d = 0; d < DA; ++d) agg1[n * DA + d] = acc[d];
}

// ---- graph segment bounds via binary search on sorted batch ----
__global__ void k_gstart(const int* __restrict__ batch, int* __restrict__ gstart){
  int g = blockIdx.x * 256 + threadIdx.x;
  if (g > NG) return;
  if (g == NG){ gstart[NG] = NN; return; }
  int lo = 0, hi = NN;
  while (lo < hi){
    int mid = (lo + hi) >> 1;
    if (batch[mid] < g) lo = mid + 1; else hi = mid;
  }
  gstart[g] = lo;
}

// ---- fused layer2-aggregate + pool: wave per graph, zero atomics ----
// pooled[g,k] = sum over n in g of: dinv[n]^2*h1[n,k] + sum_{e:dst=n} dinv[s]dinv[n]*h1[s,k]
// with h1[s] = relu(agg1[s] @ W1 + b1) recomputed in registers.
__global__ void k_l2pool(const float* __restrict__ agg1, const float* __restrict__ dinv,
                         const int* __restrict__ rowoff, const int* __restrict__ csrsrc,
                         const int* __restrict__ gstart, const float* __restrict__ wc,
                         float* __restrict__ pooled){
  __shared__ float w1S[DA * HH];
  __shared__ float b1S[HH];
  int t = threadIdx.x;
  for (int i = t; i < DA * HH; i += 256) w1S[i] = wc[OW1 + i];
  if (t < HH) b1S[t] = wc[OB1 + t];
  __syncthreads();
  int g = blockIdx.x * 4 + (t >> 6);
  int lane = t & 63;
  if (g >= NG) return;
  int a = gstart[g], b = gstart[g + 1];
  int k = lane * 2;
  float bk0 = b1S[k], bk1 = b1S[k + 1];
  float s0 = 0.f, s1 = 0.f;
  for (int n = a; n < b; ++n){
    float dn = dinv[n];
    // self term
    float v0 = bk0, v1 = bk1;
    #pragma unroll
    for (int d = 0; d < DA; ++d){
      float av = agg1[n * DA + d];
      v0 += av * w1S[d * HH + k];
      v1 += av * w1S[d * HH + k + 1];
    }
    float cs = dn * dn;
    s0 += fmaxf(v0, 0.f) * cs;
    s1 += fmaxf(v1, 0.f) * cs;
    // incoming edges of n
    int e0 = rowoff[n], e1 = rowoff[n + 1];
    for (int j = e0; j < e1; ++j){
      int s = csrsrc[j];
      float c = dinv[s] * dn;
      float u0 = bk0, u1 = bk1;
      #pragma unroll
      for (int d = 0; d < DA; ++d){
        float av = agg1[s * DA + d];
        u0 += av * w1S[d * HH + k];
        u1 += av * w1S[d * HH + k + 1];
      }
      s0 += fmaxf(u0, 0.f) * c;
      s1 += fmaxf(u1, 0.f) * c;
    }
  }
  pooled[(size_t)g * HH + k]     = s0;
  pooled[(size_t)g * HH + k + 1] = s1;
}

// ---- gemb = (pooled/cnt) @ W2 + (cnt>0 ? b2 : 0) ----
__global__ void k_gemm1(const float* __restrict__ pooled, const float* __restrict__ wc,
                        const int* __restrict__ gstart, float* __restrict__ gemb){
  __shared__ float pl[2][HH];
  int t = threadIdx.x;
  int gg = t >> 7, k = t & 127;
  for (int p = blockIdx.x; p < NG / 2; p += gridDim.x){
    int g = p * 2 + gg;
    int cnt = gstart[g + 1] - gstart[g];
    float inv = 1.0f / (float)(cnt > 1 ? cnt : 1);
    pl[gg][k] = pooled[(size_t)g * HH + k] * inv;
    __syncthreads();
    float acc = (cnt > 0) ? wc[OB2 + k] : 0.f;
    #pragma unroll 8
    for (int d = 0; d < HH; ++d) acc += pl[gg][d] * wc[OW2 + d * HH + k];
    gemb[(size_t)g * HH + k] = acc;
    __syncthreads();
  }
}

// ---- out = gemb @ Wfc + bfc, store dtype per flag ----
__global__ void k_gemm2(const float* __restrict__ gemb, const float* __restrict__ wc,
                        const int* __restrict__ flag, void* __restrict__ out){
  __shared__ float pl[2][HH];
  int t = threadIdx.x;
  int isf32 = flag[0];
  int gg = t >> 7, k = t & 127;
  for (int p = blockIdx.x; p < NG / 2; p += gridDim.x){
    int g = p * 2 + gg;
    pl[gg][k] = gemb[(size_t)g * HH + k];
    __syncthreads();
    float acc = wc[OBFC + k];
    #pragma unroll 8
    for (int d = 0; d < HH; ++d) acc += pl[gg][d] * wc[OWFC + d * HH + k];
    if (isf32) ((float*)out)[(size_t)g * HH + k] = acc;
    else       ((u16*)out)[(size_t)g * HH + k] = f2bf(acc);
    __syncthreads();
  }
}

extern "C" void kernel_launch(void* const* d_in, const int* in_sizes, int n_in,
                              void* d_out, int out_size, void* d_ws, size_t ws_size,
                              hipStream_t stream){
  const int* x     = (const int*)d_in[0];
  const int* ei    = (const int*)d_in[1];
  const int* batch = (const int*)d_in[3];
  const void* aemb = d_in[4];
  const void* W1   = d_in[6];
  const void* b1   = d_in[7];
  const void* W2   = d_in[8];
  const void* b2   = d_in[9];
  const void* Wfc  = d_in[10];
  const void* bfc  = d_in[11];
  const int* srcp = ei;
  const int* dstp = ei + NE;

  // workspace layout — ~29.3 MB (ws_size known to be >= this, < 107 MB)
  char* p = (char*)d_ws;
  int*   flag   = (int*)p;                 p += 64;
  float* wc     = (float*)p;               p += sizeof(float) * ((NWC + 15) & ~15);
  int*   degcur = (int*)p;                 p += sizeof(int) * NN;          // deg, then cursor
  int*   rowoff = (int*)p;                 p += sizeof(int) * (NN + 1);
  int*   part   = (int*)p;                 p += sizeof(int) * 512;
  float* dinv   = (float*)p;               p += sizeof(float) * NN;
  int*   csrsrc = (int*)p;                 p += sizeof(int) * NE;
  int*   gstart = (int*)p;                 p += sizeof(int) * (NG + 4);
  float* pooled = (float*)p;               p += sizeof(float) * (size_t)NG * HH;
  float* h0     = (float*)p;               // NN*DA f32; gemb aliases (h0 dead by gemm1)
  float* gemb   = h0;                      p += sizeof(float) * (size_t)NN * DA;
  float* agg1   = (float*)p;               p += sizeof(float) * (size_t)NN * DA;
  (void)p; (void)ws_size; (void)n_in; (void)in_sizes; (void)out_size;

  k_detect<<<1, 256, 0, stream>>>((const u16*)aemb, flag);
  k_cvtw  <<<(NWC + 255) / 256, 256, 0, stream>>>(aemb, W1, b1, W2, b2, Wfc, bfc, flag, wc);
  k_zero  <<<(NN + 255) / 256, 256, 0, stream>>>(degcur);
  k_deg   <<<(NE + 255) / 256, 256, 0, stream>>>(dstp, degcur);
  k_scan1 <<<NCHUNK, 256, 0, stream>>>(degcur, rowoff, part);
  k_scan2 <<<1, 512, 0, stream>>>(part);
  k_scan3 <<<(NN + 255) / 256, 256, 0, stream>>>(degcur, rowoff, dinv, part);
  k_fill  <<<(NE + 255) / 256, 256, 0, stream>>>(srcp, dstp, degcur, csrsrc);
  k_embed0<<<(NN + 255) / 256, 256, 0, stream>>>(x, wc, h0);
  k_l1csr <<<(NN + 255) / 256, 256, 0, stream>>>(h0, agg1, rowoff, csrsrc, dinv);
  k_gstart<<<(NG + 256) / 256, 256, 0, stream>>>(batch, gstart);
  k_l2pool<<<NG / 4, 256, 0, stream>>>(agg1, dinv, rowoff, csrsrc, gstart, wc, pooled);
  k_gemm1 <<<600, 256, 0, stream>>>(pooled, wc, gstart, gemb);
  k_gemm2 <<<600, 256, 0, stream>>>(gemb, wc, flag, d_out);
}

// Round 5
// 366.450 us; speedup vs baseline: 3.7436x; 1.0976x over previous
//
#include <hip/hip_runtime.h>

#define NN 300000
#define NE 600000
#define NG 12000
#define HH 128
#define FA 9
#define VA 119
#define DA 9
#define AGS 5                          // agg1 packed row stride in uints (10 bf16)
#define NCHUNK ((NN + 1023) / 1024)   // 293

// canonical f32 weight scratch offsets
#define OEMB 0
#define OW1  (FA*VA*DA)            // 9639
#define OB1  (OW1 + DA*HH)         // 10791
#define OW2  (OB1 + HH)            // 10919
#define OB2  (OW2 + HH*HH)         // 27303
#define OWFC (OB2 + HH)            // 27431
#define OBFC (OWFC + HH*HH)        // 43815
#define NWC  (OBFC + HH)           // 43943

typedef unsigned short u16;
typedef unsigned int u32;

__device__ __forceinline__ float bf2f(u16 u){
  union { u32 i; float f; } v; v.i = ((u32)u) << 16; return v.f;
}
__device__ __forceinline__ float bflo(u32 w){
  union { u32 i; float f; } v; v.i = w << 16; return v.f;
}
__device__ __forceinline__ float bfhi(u32 w){
  union { u32 i; float f; } v; v.i = w & 0xFFFF0000u; return v.f;
}
__device__ __forceinline__ u16 f2bf(float f){
  union { float f; u32 i; } v; v.f = f;
  u32 x = v.i;
  return (u16)((x + 0x7FFFu + ((x >> 16) & 1u)) >> 16);
}
__device__ __forceinline__ float ldf(const void* p, int i, int isf32){
  return isf32 ? ((const float*)p)[i] : bf2f(((const u16*)p)[i]);
}

// ---- dtype detector (validated round 3: picks bf16 correctly) ----
__global__ void k_detect(const u16* __restrict__ emb, int* __restrict__ flag){
  __shared__ int cnt;
  int t = threadIdx.x;
  if (t == 0) cnt = 0;
  __syncthreads();
  u16 u = emb[t];
  int e = (u >> 7) & 0xFF;
  if (e >= 96 && e < 126) atomicAdd(&cnt, 1);
  __syncthreads();
  if (t == 0) flag[0] = (cnt >= 200) ? 0 : 1;   // 0 = bf16, 1 = f32
}

// ---- canonicalize params to f32 scratch; also zero degcur (fused) ----
__global__ void k_cvtw(const void* emb, const void* W1, const void* b1,
                       const void* W2, const void* b2, const void* Wfc,
                       const void* bfc, const int* __restrict__ flag,
                       float* __restrict__ wc, int* __restrict__ degcur){
  int i = blockIdx.x * 256 + threadIdx.x;
  if (i < NN) degcur[i] = 0;
  if (i >= NWC) return;
  int f = flag[0];
  float v;
  if      (i < OW1)  v = ldf(emb, i - OEMB, f);
  else if (i < OB1)  v = ldf(W1,  i - OW1,  f);
  else if (i < OW2)  v = ldf(b1,  i - OB1,  f);
  else if (i < OB2)  v = ldf(W2,  i - OW2,  f);
  else if (i < OWFC) v = ldf(b2,  i - OB2,  f);
  else if (i < OBFC) v = ldf(Wfc, i - OWFC, f);
  else               v = ldf(bfc, i - OBFC, f);
  wc[i] = v;
}

// ---- in-degree histogram ----
__global__ void k_deg(const int* __restrict__ dst, int* __restrict__ deg){
  int e = blockIdx.x * 256 + threadIdx.x;
  if (e < NE) atomicAdd(&deg[dst[e]], 1);
}

// ---- exclusive scan of deg -> rowoff (3-kernel) ----
__global__ void k_scan1(const int* __restrict__ deg, int* __restrict__ rowoff,
                        int* __restrict__ part){
  __shared__ int sh[256];
  int base = blockIdx.x * 1024;
  int t = threadIdx.x;
  int i0 = base + t * 4;
  int v0=0, v1=0, v2=0, v3=0;
  if (i0 + 0 < NN) v0 = deg[i0 + 0];
  if (i0 + 1 < NN) v1 = deg[i0 + 1];
  if (i0 + 2 < NN) v2 = deg[i0 + 2];
  if (i0 + 3 < NN) v3 = deg[i0 + 3];
  int tsum = v0 + v1 + v2 + v3;
  sh[t] = tsum;
  __syncthreads();
  for (int off = 1; off < 256; off <<= 1){
    int add = (t >= off) ? sh[t - off] : 0;
    __syncthreads();
    sh[t] += add;
    __syncthreads();
  }
  int run = sh[t] - tsum;
  if (t == 255) part[blockIdx.x] = sh[255];
  if (i0 + 0 < NN){ rowoff[i0 + 0] = run; run += v0; }
  if (i0 + 1 < NN){ rowoff[i0 + 1] = run; run += v1; }
  if (i0 + 2 < NN){ rowoff[i0 + 2] = run; run += v2; }
  if (i0 + 3 < NN){ rowoff[i0 + 3] = run; run += v3; }
}

__global__ void k_scan2(int* __restrict__ part){
  __shared__ int sh[512];
  int t = threadIdx.x;
  int v = (t < NCHUNK) ? part[t] : 0;
  sh[t] = v;
  __syncthreads();
  for (int off = 1; off < 512; off <<= 1){
    int add = (t >= off) ? sh[t - off] : 0;
    __syncthreads();
    sh[t] += add;
    __syncthreads();
  }
  if (t < NCHUNK) part[t] = sh[t] - v;
}

// degcur: deg on input, cursor on output
__global__ void k_scan3(int* degcur, int* __restrict__ rowoff,
                        float* __restrict__ dinv, const int* __restrict__ part){
  int i = blockIdx.x * 256 + threadIdx.x;
  if (i < NN){
    float dv = (float)degcur[i];
    int r = rowoff[i] + part[i >> 10];
    rowoff[i] = r;
    degcur[i] = r;
    dinv[i] = rsqrtf(dv + 1.0f);
  }
  if (i == 0) rowoff[NN] = NE;
}

// ---- CSR fill: entry = {src, coef = dinv[src]*dinv[dst]} ----
__global__ void k_fill(const int* __restrict__ src, const int* __restrict__ dst,
                       int* __restrict__ cursor, const float* __restrict__ dinv,
                       uint2* __restrict__ csr){
  int e = blockIdx.x * 256 + threadIdx.x;
  if (e < NE){
    int s = src[e], d = dst[e];
    int pos = atomicAdd(&cursor[d], 1);
    uint2 ent;
    ent.x = (u32)s;
    ent.y = __float_as_uint(dinv[s] * dinv[d]);
    csr[pos] = ent;
  }
}

// ---- multi_embed (+ fused gstart binary search for n <= NG) ----
__global__ void k_embed0(const int* __restrict__ x, const float* __restrict__ wc,
                         const int* __restrict__ batch, int* __restrict__ gstart,
                         float* __restrict__ h0){
  __shared__ float embS[FA * VA * DA];   // 38.6 KB
  int t = threadIdx.x;
  for (int i = t; i < FA * VA * DA; i += 256) embS[i] = wc[OEMB + i];
  __syncthreads();
  int n = blockIdx.x * 256 + t;
  if (n <= NG){
    if (n == NG) gstart[NG] = NN;
    else {
      int lo = 0, hi = NN;
      while (lo < hi){
        int mid = (lo + hi) >> 1;
        if (batch[mid] < n) lo = mid + 1; else hi = mid;
      }
      gstart[n] = lo;
    }
  }
  if (n >= NN) return;
  int idx[FA];
  #pragma unroll
  for (int f = 0; f < FA; ++f) idx[f] = x[n * FA + f];
  #pragma unroll
  for (int d = 0; d < DA; ++d){
    float a = 0.f;
    #pragma unroll
    for (int f = 0; f < FA; ++f) a += embS[(f * VA + idx[f]) * DA + d];
    h0[n * DA + d] = a;
  }
}

// ---- layer-1 CSR gather: agg1 = A' h0, packed bf16 (stride 10 halves) ----
__global__ void k_l1csr(const float* __restrict__ h0, u32* __restrict__ agg1u,
                        const int* __restrict__ rowoff, const uint2* __restrict__ csr,
                        const float* __restrict__ dinv){
  int n = blockIdx.x * 256 + threadIdx.x;
  if (n >= NN) return;
  float di = dinv[n];
  float c0 = di * di;
  float acc[DA];
  #pragma unroll
  for (int d = 0; d < DA; ++d) acc[d] = c0 * h0[n * DA + d];
  int s0 = rowoff[n], s1 = rowoff[n + 1];
  for (int j = s0; j < s1; ++j){
    uint2 ent = csr[j];
    int s = (int)ent.x;
    float c = __uint_as_float(ent.y);
    #pragma unroll
    for (int d = 0; d < DA; ++d) acc[d] += c * h0[s * DA + d];
  }
  int b = n * AGS;
  #pragma unroll
  for (int q = 0; q < 4; ++q)
    agg1u[b + q] = (u32)f2bf(acc[2*q]) | ((u32)f2bf(acc[2*q+1]) << 16);
  agg1u[b + 4] = (u32)f2bf(acc[8]);
}

// ---- fused layer2-aggregate + pool: wave per graph, W1 in registers,
//      flat edge window with precomputed coefs, unroll x4 ----
__global__ void k_l2pool(const u32* __restrict__ agg1u, const float* __restrict__ dinv,
                         const int* __restrict__ rowoff, const uint2* __restrict__ csr,
                         const int* __restrict__ gstart, const float* __restrict__ wc,
                         float* __restrict__ pooled){
  int t = threadIdx.x;
  int g = blockIdx.x * 4 + (t >> 6);
  int lane = t & 63;
  if (g >= NG) return;
  int k = lane * 2;
  float wA[DA], wB[DA];
  #pragma unroll
  for (int d = 0; d < DA; ++d){
    wA[d] = wc[OW1 + d * HH + k];
    wB[d] = wc[OW1 + d * HH + k + 1];
  }
  float bA = wc[OB1 + k], bB = wc[OB1 + k + 1];

  int a = gstart[g], b = gstart[g + 1];
  float s0 = 0.f, s1 = 0.f;

  // self terms: coef = dinv[n]^2, rows contiguous
  for (int n = a; n < b; ++n){
    float dn = dinv[n];
    float c = dn * dn;
    int base = n * AGS;
    u32 r0 = agg1u[base], r1 = agg1u[base+1], r2 = agg1u[base+2],
        r3 = agg1u[base+3], r4 = agg1u[base+4];
    float v0 = bA, v1 = bB;
    float e0=bflo(r0), e1=bfhi(r0), e2=bflo(r1), e3=bfhi(r1), e4=bflo(r2),
          e5=bfhi(r2), e6=bflo(r3), e7=bfhi(r3), e8=bflo(r4);
    v0 += e0*wA[0]+e1*wA[1]+e2*wA[2]+e3*wA[3]+e4*wA[4]+e5*wA[5]+e6*wA[6]+e7*wA[7]+e8*wA[8];
    v1 += e0*wB[0]+e1*wB[1]+e2*wB[2]+e3*wB[3]+e4*wB[4]+e5*wB[5]+e6*wB[6]+e7*wB[7]+e8*wB[8];
    s0 += fmaxf(v0, 0.f) * c;
    s1 += fmaxf(v1, 0.f) * c;
  }

  // edge terms: flat window, unroll 4
  int j = rowoff[a], jend = rowoff[b];
  #define EDGE_BODY(ENT)                                                          \
    {                                                                             \
      int base = (int)(ENT).x * AGS;                                              \
      float c = __uint_as_float((ENT).y);                                         \
      u32 r0 = agg1u[base], r1 = agg1u[base+1], r2 = agg1u[base+2],               \
          r3 = agg1u[base+3], r4 = agg1u[base+4];                                 \
      float v0 = bA, v1 = bB;                                                     \
      float e0=bflo(r0), e1=bfhi(r0), e2=bflo(r1), e3=bfhi(r1), e4=bflo(r2),      \
            e5=bfhi(r2), e6=bflo(r3), e7=bfhi(r3), e8=bflo(r4);                   \
      v0 += e0*wA[0]+e1*wA[1]+e2*wA[2]+e3*wA[3]+e4*wA[4]+e5*wA[5]+e6*wA[6]+e7*wA[7]+e8*wA[8]; \
      v1 += e0*wB[0]+e1*wB[1]+e2*wB[2]+e3*wB[3]+e4*wB[4]+e5*wB[5]+e6*wB[6]+e7*wB[7]+e8*wB[8]; \
      s0 += fmaxf(v0, 0.f) * c;                                                   \
      s1 += fmaxf(v1, 0.f) * c;                                                   \
    }
  for (; j + 3 < jend; j += 4){
    uint2 eA = csr[j], eB = csr[j+1], eC = csr[j+2], eD = csr[j+3];
    EDGE_BODY(eA) EDGE_BODY(eB) EDGE_BODY(eC) EDGE_BODY(eD)
  }
  for (; j < jend; ++j){
    uint2 eA = csr[j];
    EDGE_BODY(eA)
  }
  #undef EDGE_BODY

  pooled[(size_t)g * HH + k]     = s0;
  pooled[(size_t)g * HH + k + 1] = s1;
}

// ---- gemb = (pooled/cnt) @ W2 + (cnt>0 ? b2 : 0) ----
__global__ void k_gemm1(const float* __restrict__ pooled, const float* __restrict__ wc,
                        const int* __restrict__ gstart, float* __restrict__ gemb){
  __shared__ float pl[2][HH];
  int t = threadIdx.x;
  int gg = t >> 7, k = t & 127;
  for (int p = blockIdx.x; p < NG / 2; p += gridDim.x){
    int g = p * 2 + gg;
    int cnt = gstart[g + 1] - gstart[g];
    float inv = 1.0f / (float)(cnt > 1 ? cnt : 1);
    pl[gg][k] = pooled[(size_t)g * HH + k] * inv;
    __syncthreads();
    float acc = (cnt > 0) ? wc[OB2 + k] : 0.f;
    #pragma unroll 8
    for (int d = 0; d < HH; ++d) acc += pl[gg][d] * wc[OW2 + d * HH + k];
    gemb[(size_t)g * HH + k] = acc;
    __syncthreads();
  }
}

// ---- out = gemb @ Wfc + bfc, store dtype per flag ----
__global__ void k_gemm2(const float* __restrict__ gemb, const float* __restrict__ wc,
                        const int* __restrict__ flag, void* __restrict__ out){
  __shared__ float pl[2][HH];
  int t = threadIdx.x;
  int isf32 = flag[0];
  int gg = t >> 7, k = t & 127;
  for (int p = blockIdx.x; p < NG / 2; p += gridDim.x){
    int g = p * 2 + gg;
    pl[gg][k] = gemb[(size_t)g * HH + k];
    __syncthreads();
    float acc = wc[OBFC + k];
    #pragma unroll 8
    for (int d = 0; d < HH; ++d) acc += pl[gg][d] * wc[OWFC + d * HH + k];
    if (isf32) ((float*)out)[(size_t)g * HH + k] = acc;
    else       ((u16*)out)[(size_t)g * HH + k] = f2bf(acc);
    __syncthreads();
  }
}

extern "C" void kernel_launch(void* const* d_in, const int* in_sizes, int n_in,
                              void* d_out, int out_size, void* d_ws, size_t ws_size,
                              hipStream_t stream){
  const int* x     = (const int*)d_in[0];
  const int* ei    = (const int*)d_in[1];
  const int* batch = (const int*)d_in[3];
  const void* aemb = d_in[4];
  const void* W1   = d_in[6];
  const void* b1   = d_in[7];
  const void* W2   = d_in[8];
  const void* b2   = d_in[9];
  const void* Wfc  = d_in[10];
  const void* bfc  = d_in[11];
  const int* srcp = ei;
  const int* dstp = ei + NE;

  // workspace layout — ~31.6 MB (34 MB known safe from round 4)
  char* p = (char*)d_ws;
  int*   flag   = (int*)p;                 p += 64;
  float* wc     = (float*)p;               p += sizeof(float) * 43944;          // NWC padded to 8B
  int*   degcur = (int*)p;                 p += sizeof(int) * NN;               // deg, then cursor
  int*   rowoff = (int*)p;                 p += sizeof(int) * (NN + 2);
  int*   part   = (int*)p;                 p += sizeof(int) * 512;
  float* dinv   = (float*)p;               p += sizeof(float) * NN;
  uint2* csr    = (uint2*)p;               p += sizeof(uint2) * NE;             // 4.8 MB
  int*   gstart = (int*)p;                 p += sizeof(int) * (NG + 4);
  float* pooled = (float*)p;               p += sizeof(float) * (size_t)NG * HH;
  float* h0     = (float*)p;               // NN*DA f32; gemb aliases (h0 dead by gemm1)
  float* gemb   = h0;                      p += sizeof(float) * (size_t)NN * DA;
  u32*   agg1u  = (u32*)p;                 p += sizeof(u32) * (size_t)NN * AGS; // 6 MB
  (void)p; (void)ws_size; (void)n_in; (void)in_sizes; (void)out_size;

  k_detect<<<1, 256, 0, stream>>>((const u16*)aemb, flag);
  k_cvtw  <<<(NN + 255) / 256, 256, 0, stream>>>(aemb, W1, b1, W2, b2, Wfc, bfc, flag, wc, degcur);
  k_deg   <<<(NE + 255) / 256, 256, 0, stream>>>(dstp, degcur);
  k_scan1 <<<NCHUNK, 256, 0, stream>>>(degcur, rowoff, part);
  k_scan2 <<<1, 512, 0, stream>>>(part);
  k_scan3 <<<(NN + 255) / 256, 256, 0, stream>>>(degcur, rowoff, dinv, part);
  k_fill  <<<(NE + 255) / 256, 256, 0, stream>>>(srcp, dstp, degcur, dinv, csr);
  k_embed0<<<(NN + 255) / 256, 256, 0, stream>>>(x, wc, batch, gstart, h0);
  k_l1csr <<<(NN + 255) / 256, 256, 0, stream>>>(h0, agg1u, rowoff, csr, dinv);
  k_l2pool<<<NG / 4, 256, 0, stream>>>(agg1u, dinv, rowoff, csr, gstart, wc, pooled);
  k_gemm1 <<<600, 256, 0, stream>>>(pooled, wc, gstart, gemb);
  k_gemm2 <<<600, 256, 0, stream>>>(gemb, wc, flag, d_out);
}

// Round 6
// 340.727 us; speedup vs baseline: 4.0262x; 1.0755x over previous
//
#include <hip/hip_runtime.h>

#define NN 300000
#define NE 600000
#define NG 12000
#define HH 128
#define FA 9
#define VA 119
#define DA 9
#define AGS 5                          // agg1 packed row stride in uints (10 bf16)
#define NCHUNK ((NN + 1023) / 1024)   // 293

// canonical f32 weight scratch offsets
#define OEMB 0
#define OW1  (FA*VA*DA)            // 9639
#define OB1  (OW1 + DA*HH)         // 10791
#define OW2  (OB1 + HH)            // 10919
#define OB2  (OW2 + HH*HH)         // 27303
#define OWFC (OB2 + HH)            // 27431
#define OBFC (OWFC + HH*HH)        // 43815
#define NWC  (OBFC + HH)           // 43943

typedef unsigned short u16;
typedef unsigned int u32;

__device__ __forceinline__ float bf2f(u16 u){
  union { u32 i; float f; } v; v.i = ((u32)u) << 16; return v.f;
}
__device__ __forceinline__ float bflo(u32 w){
  union { u32 i; float f; } v; v.i = w << 16; return v.f;
}
__device__ __forceinline__ float bfhi(u32 w){
  union { u32 i; float f; } v; v.i = w & 0xFFFF0000u; return v.f;
}
__device__ __forceinline__ u16 f2bf(float f){
  union { float f; u32 i; } v; v.f = f;
  u32 x = v.i;
  return (u16)((x + 0x7FFFu + ((x >> 16) & 1u)) >> 16);
}
__device__ __forceinline__ float ldf(const void* p, int i, int isf32){
  return isf32 ? ((const float*)p)[i] : bf2f(((const u16*)p)[i]);
}

// ---- dtype detector (validated round 3: picks bf16 correctly) ----
__global__ void k_detect(const u16* __restrict__ emb, int* __restrict__ flag){
  __shared__ int cnt;
  int t = threadIdx.x;
  if (t == 0) cnt = 0;
  __syncthreads();
  u16 u = emb[t];
  int e = (u >> 7) & 0xFF;
  if (e >= 96 && e < 126) atomicAdd(&cnt, 1);
  __syncthreads();
  if (t == 0) flag[0] = (cnt >= 200) ? 0 : 1;   // 0 = bf16, 1 = f32
}

// ---- canonicalize params to f32 scratch; also zero degcur (fused) ----
__global__ void k_cvtw(const void* emb, const void* W1, const void* b1,
                       const void* W2, const void* b2, const void* Wfc,
                       const void* bfc, const int* __restrict__ flag,
                       float* __restrict__ wc, int* __restrict__ degcur){
  int i = blockIdx.x * 256 + threadIdx.x;
  if (i < NN) degcur[i] = 0;
  if (i >= NWC) return;
  int f = flag[0];
  float v;
  if      (i < OW1)  v = ldf(emb, i - OEMB, f);
  else if (i < OB1)  v = ldf(W1,  i - OW1,  f);
  else if (i < OW2)  v = ldf(b1,  i - OB1,  f);
  else if (i < OB2)  v = ldf(W2,  i - OW2,  f);
  else if (i < OWFC) v = ldf(b2,  i - OB2,  f);
  else if (i < OBFC) v = ldf(Wfc, i - OWFC, f);
  else               v = ldf(bfc, i - OBFC, f);
  wc[i] = v;
}

// ---- in-degree histogram ----
__global__ void k_deg(const int* __restrict__ dst, int* __restrict__ deg){
  int e = blockIdx.x * 256 + threadIdx.x;
  if (e < NE) atomicAdd(&deg[dst[e]], 1);
}

// ---- exclusive scan of deg -> rowoff (3-kernel) ----
__global__ void k_scan1(const int* __restrict__ deg, int* __restrict__ rowoff,
                        int* __restrict__ part){
  __shared__ int sh[256];
  int base = blockIdx.x * 1024;
  int t = threadIdx.x;
  int i0 = base + t * 4;
  int v0=0, v1=0, v2=0, v3=0;
  if (i0 + 0 < NN) v0 = deg[i0 + 0];
  if (i0 + 1 < NN) v1 = deg[i0 + 1];
  if (i0 + 2 < NN) v2 = deg[i0 + 2];
  if (i0 + 3 < NN) v3 = deg[i0 + 3];
  int tsum = v0 + v1 + v2 + v3;
  sh[t] = tsum;
  __syncthreads();
  for (int off = 1; off < 256; off <<= 1){
    int add = (t >= off) ? sh[t - off] : 0;
    __syncthreads();
    sh[t] += add;
    __syncthreads();
  }
  int run = sh[t] - tsum;
  if (t == 255) part[blockIdx.x] = sh[255];
  if (i0 + 0 < NN){ rowoff[i0 + 0] = run; run += v0; }
  if (i0 + 1 < NN){ rowoff[i0 + 1] = run; run += v1; }
  if (i0 + 2 < NN){ rowoff[i0 + 2] = run; run += v2; }
  if (i0 + 3 < NN){ rowoff[i0 + 3] = run; run += v3; }
}

__global__ void k_scan2(int* __restrict__ part){
  __shared__ int sh[512];
  int t = threadIdx.x;
  int v = (t < NCHUNK) ? part[t] : 0;
  sh[t] = v;
  __syncthreads();
  for (int off = 1; off < 512; off <<= 1){
    int add = (t >= off) ? sh[t - off] : 0;
    __syncthreads();
    sh[t] += add;
    __syncthreads();
  }
  if (t < NCHUNK) part[t] = sh[t] - v;
}

// degcur: deg on input, cursor on output
__global__ void k_scan3(int* degcur, int* __restrict__ rowoff,
                        float* __restrict__ dinv, const int* __restrict__ part){
  int i = blockIdx.x * 256 + threadIdx.x;
  if (i < NN){
    float dv = (float)degcur[i];
    int r = rowoff[i] + part[i >> 10];
    rowoff[i] = r;
    degcur[i] = r;
    dinv[i] = rsqrtf(dv + 1.0f);
  }
  if (i == 0) rowoff[NN] = NE;
}

// ---- CSR fill: entry = {src, coef = dinv[src]*dinv[dst]} ----
__global__ void k_fill(const int* __restrict__ src, const int* __restrict__ dst,
                       int* __restrict__ cursor, const float* __restrict__ dinv,
                       uint2* __restrict__ csr){
  int e = blockIdx.x * 256 + threadIdx.x;
  if (e < NE){
    int s = src[e], d = dst[e];
    int pos = atomicAdd(&cursor[d], 1);
    uint2 ent;
    ent.x = (u32)s;
    ent.y = __float_as_uint(dinv[s] * dinv[d]);
    csr[pos] = ent;
  }
}

// ---- multi_embed (+ fused gstart binary search for n <= NG) ----
__global__ void k_embed0(const int* __restrict__ x, const float* __restrict__ wc,
                         const int* __restrict__ batch, int* __restrict__ gstart,
                         float* __restrict__ h0){
  __shared__ float embS[FA * VA * DA];   // 38.6 KB
  int t = threadIdx.x;
  for (int i = t; i < FA * VA * DA; i += 256) embS[i] = wc[OEMB + i];
  __syncthreads();
  int n = blockIdx.x * 256 + t;
  if (n <= NG){
    if (n == NG) gstart[NG] = NN;
    else {
      int lo = 0, hi = NN;
      while (lo < hi){
        int mid = (lo + hi) >> 1;
        if (batch[mid] < n) lo = mid + 1; else hi = mid;
      }
      gstart[n] = lo;
    }
  }
  if (n >= NN) return;
  int idx[FA];
  #pragma unroll
  for (int f = 0; f < FA; ++f) idx[f] = x[n * FA + f];
  #pragma unroll
  for (int d = 0; d < DA; ++d){
    float a = 0.f;
    #pragma unroll
    for (int f = 0; f < FA; ++f) a += embS[(f * VA + idx[f]) * DA + d];
    h0[n * DA + d] = a;
  }
}

// ---- layer-1 CSR gather: agg1 = A' h0, packed bf16 (stride 10 halves) ----
__global__ void k_l1csr(const float* __restrict__ h0, u32* __restrict__ agg1u,
                        const int* __restrict__ rowoff, const uint2* __restrict__ csr,
                        const float* __restrict__ dinv){
  int n = blockIdx.x * 256 + threadIdx.x;
  if (n >= NN) return;
  float di = dinv[n];
  float c0 = di * di;
  float acc[DA];
  #pragma unroll
  for (int d = 0; d < DA; ++d) acc[d] = c0 * h0[n * DA + d];
  int s0 = rowoff[n], s1 = rowoff[n + 1];
  for (int j = s0; j < s1; ++j){
    uint2 ent = csr[j];
    int s = (int)ent.x;
    float c = __uint_as_float(ent.y);
    #pragma unroll
    for (int d = 0; d < DA; ++d) acc[d] += c * h0[s * DA + d];
  }
  int b = n * AGS;
  #pragma unroll
  for (int q = 0; q < 4; ++q)
    agg1u[b + q] = (u32)f2bf(acc[2*q]) | ((u32)f2bf(acc[2*q+1]) << 16);
  agg1u[b + 4] = (u32)f2bf(acc[8]);
}

// ---- fused layer2-aggregate + pool: wave per graph. All loop bounds are
//      rooted in readfirstlane so every address (csr entry, agg1 row, dinv)
//      is provably wave-uniform -> scalar loads; bf16 unpack on scalar pipe;
//      VALU does only the 18 v_fma (SGPR operand) + epilogue per item. ----
__global__ void k_l2pool(const u32* __restrict__ agg1u, const float* __restrict__ dinv,
                         const int* __restrict__ rowoff, const uint2* __restrict__ csr,
                         const int* __restrict__ gstart, const float* __restrict__ wc,
                         float* __restrict__ pooled){
  int t = threadIdx.x;
  int g = blockIdx.x * 4 + (t >> 6);
  int lane = t & 63;
  if (g >= NG) return;
  int k = lane * 2;
  float wA[DA], wB[DA];
  #pragma unroll
  for (int d = 0; d < DA; ++d){
    wA[d] = wc[OW1 + d * HH + k];
    wB[d] = wc[OW1 + d * HH + k + 1];
  }
  float bA = wc[OB1 + k], bB = wc[OB1 + k + 1];

  int a    = __builtin_amdgcn_readfirstlane(gstart[g]);
  int b    = __builtin_amdgcn_readfirstlane(gstart[g + 1]);
  float s0 = 0.f, s1 = 0.f;

  #define ITEM_BODY(BASE, CF)                                                     \
    {                                                                             \
      u32 r0 = agg1u[(BASE)], r1 = agg1u[(BASE)+1], r2 = agg1u[(BASE)+2],         \
          r3 = agg1u[(BASE)+3], r4 = agg1u[(BASE)+4];                             \
      float v0 = bA, v1 = bB;                                                     \
      float e0=bflo(r0), e1=bfhi(r0), e2=bflo(r1), e3=bfhi(r1), e4=bflo(r2),      \
            e5=bfhi(r2), e6=bflo(r3), e7=bfhi(r3), e8=bflo(r4);                   \
      v0 += e0*wA[0]+e1*wA[1]+e2*wA[2]+e3*wA[3]+e4*wA[4]+e5*wA[5]+e6*wA[6]+e7*wA[7]+e8*wA[8]; \
      v1 += e0*wB[0]+e1*wB[1]+e2*wB[2]+e3*wB[3]+e4*wB[4]+e5*wB[5]+e6*wB[6]+e7*wB[7]+e8*wB[8]; \
      s0 += fmaxf(v0, 0.f) * (CF);                                                \
      s1 += fmaxf(v1, 0.f) * (CF);                                                \
    }

  // self terms: n uniform -> scalar loads
  for (int n = a; n < b; ++n){
    float dn = dinv[n];
    float c = dn * dn;
    ITEM_BODY(n * AGS, c)
  }

  // edge terms: flat uniform window, unroll x2
  int j    = __builtin_amdgcn_readfirstlane(rowoff[a]);
  int jend = __builtin_amdgcn_readfirstlane(rowoff[b]);
  for (; j + 1 < jend; j += 2){
    uint2 eA = csr[j], eB = csr[j + 1];
    int baseA = (int)eA.x * AGS;  float cA = __uint_as_float(eA.y);
    int baseB = (int)eB.x * AGS;  float cB = __uint_as_float(eB.y);
    ITEM_BODY(baseA, cA)
    ITEM_BODY(baseB, cB)
  }
  if (j < jend){
    uint2 eA = csr[j];
    ITEM_BODY((int)eA.x * AGS, __uint_as_float(eA.y))
  }
  #undef ITEM_BODY

  pooled[(size_t)g * HH + k]     = s0;
  pooled[(size_t)g * HH + k + 1] = s1;
}

// ---- fused head: out = ((pooled/cnt) @ W2 + b2?) @ Wfc + bfc ----
__global__ void k_head(const float* __restrict__ pooled, const float* __restrict__ wc,
                       const int* __restrict__ gstart, const int* __restrict__ flag,
                       void* __restrict__ out){
  __shared__ float pl[2][HH];
  __shared__ float ge[2][HH];
  int t = threadIdx.x;
  int isf32 = flag[0];
  int gg = t >> 7, k = t & 127;
  for (int p = blockIdx.x; p < NG / 2; p += gridDim.x){
    int g = p * 2 + gg;
    int cnt = gstart[g + 1] - gstart[g];
    float inv = 1.0f / (float)(cnt > 1 ? cnt : 1);
    pl[gg][k] = pooled[(size_t)g * HH + k] * inv;
    __syncthreads();
    float acc = (cnt > 0) ? wc[OB2 + k] : 0.f;
    #pragma unroll 8
    for (int d = 0; d < HH; ++d) acc += pl[gg][d] * wc[OW2 + d * HH + k];
    ge[gg][k] = acc;
    __syncthreads();
    float o = wc[OBFC + k];
    #pragma unroll 8
    for (int d = 0; d < HH; ++d) o += ge[gg][d] * wc[OWFC + d * HH + k];
    if (isf32) ((float*)out)[(size_t)g * HH + k] = o;
    else       ((u16*)out)[(size_t)g * HH + k] = f2bf(o);
    __syncthreads();
  }
}

extern "C" void kernel_launch(void* const* d_in, const int* in_sizes, int n_in,
                              void* d_out, int out_size, void* d_ws, size_t ws_size,
                              hipStream_t stream){
  const int* x     = (const int*)d_in[0];
  const int* ei    = (const int*)d_in[1];
  const int* batch = (const int*)d_in[3];
  const void* aemb = d_in[4];
  const void* W1   = d_in[6];
  const void* b1   = d_in[7];
  const void* W2   = d_in[8];
  const void* b2   = d_in[9];
  const void* Wfc  = d_in[10];
  const void* bfc  = d_in[11];
  const int* srcp = ei;
  const int* dstp = ei + NE;

  // workspace layout — ~31.6 MB (34 MB known safe from round 4)
  char* p = (char*)d_ws;
  int*   flag   = (int*)p;                 p += 64;
  float* wc     = (float*)p;               p += sizeof(float) * 43944;          // NWC padded
  int*   degcur = (int*)p;                 p += sizeof(int) * NN;               // deg, then cursor
  int*   rowoff = (int*)p;                 p += sizeof(int) * (NN + 2);
  int*   part   = (int*)p;                 p += sizeof(int) * 512;
  float* dinv   = (float*)p;               p += sizeof(float) * NN;
  uint2* csr    = (uint2*)p;               p += sizeof(uint2) * NE;             // 4.8 MB
  int*   gstart = (int*)p;                 p += sizeof(int) * (NG + 4);
  float* pooled = (float*)p;               p += sizeof(float) * (size_t)NG * HH;
  float* h0     = (float*)p;               p += sizeof(float) * (size_t)NN * DA;
  u32*   agg1u  = (u32*)p;                 p += sizeof(u32) * (size_t)NN * AGS; // 6 MB
  (void)p; (void)ws_size; (void)n_in; (void)in_sizes; (void)out_size;

  k_detect<<<1, 256, 0, stream>>>((const u16*)aemb, flag);
  k_cvtw  <<<(NN + 255) / 256, 256, 0, stream>>>(aemb, W1, b1, W2, b2, Wfc, bfc, flag, wc, degcur);
  k_deg   <<<(NE + 255) / 256, 256, 0, stream>>>(dstp, degcur);
  k_scan1 <<<NCHUNK, 256, 0, stream>>>(degcur, rowoff, part);
  k_scan2 <<<1, 512, 0, stream>>>(part);
  k_scan3 <<<(NN + 255) / 256, 256, 0, stream>>>(degcur, rowoff, dinv, part);
  k_fill  <<<(NE + 255) / 256, 256, 0, stream>>>(srcp, dstp, degcur, dinv, csr);
  k_embed0<<<(NN + 255) / 256, 256, 0, stream>>>(x, wc, batch, gstart, h0);
  k_l1csr <<<(NN + 255) / 256, 256, 0, stream>>>(h0, agg1u, rowoff, csr, dinv);
  k_l2pool<<<NG / 4, 256, 0, stream>>>(agg1u, dinv, rowoff, csr, gstart, wc, pooled);
  k_head  <<<600, 256, 0, stream>>>(pooled, wc, gstart, flag, d_out);
}